// Round 2
// baseline (333.725 us; speedup 1.0000x reference)
//
#include <hip/hip_runtime.h>

#define NTOK 8192
#define DDIM 1024
#define HDIM 2048
#define ODIM 1024
#define NEXP 8
#define OUTW (ODIM + NEXP)   // 1032
#define MT2 32               // worst-case 256-row m-tiles per expert

typedef __bf16 bf16_t;
typedef bf16_t bf16x8 __attribute__((ext_vector_type(8)));
typedef bf16_t bf16x4 __attribute__((ext_vector_type(4)));
typedef float f32x4 __attribute__((ext_vector_type(4)));

__device__ __forceinline__ void gld_lds16(bf16_t* lds, const bf16_t* g) {
  __builtin_amdgcn_global_load_lds(
      (__attribute__((address_space(1))) void*)g,
      (__attribute__((address_space(3))) void*)lds, 16, 0, 0);
}

__global__ void zero_cnt_kernel(int* cnt) {
  if (threadIdx.x < NEXP) cnt[threadIdx.x] = 0;
}

// Per-block LDS histogram: 256 global atomics total instead of 8192.
__global__ void route_kernel(const int* __restrict__ idx, float* __restrict__ out,
                             int* __restrict__ rank, int* cnt) {
  __shared__ int lcnt[NEXP];
  __shared__ int lbase[NEXP];
  int t = threadIdx.x;
  if (t < NEXP) lcnt[t] = 0;
  __syncthreads();
  int n = blockIdx.x * 256 + t;
  int e = idx[n];
  int lr = atomicAdd(&lcnt[e], 1);
  __syncthreads();
  if (t < NEXP) lbase[t] = atomicAdd(&cnt[t], lcnt[t]);
  __syncthreads();
  rank[n] = lbase[e] + lr;
  float* o = out + (size_t)n * OUTW + ODIM;
#pragma unroll
  for (int j = 0; j < NEXP; j++) o[j] = (j == e) ? 1.0f : 0.0f;
}

__global__ void scan_kernel(const int* __restrict__ cnt, int* __restrict__ off) {
  if (threadIdx.x == 0) {
    int s = 0;
    for (int e = 0; e < NEXP; e++) { off[e] = s; s += cnt[e]; }
  }
}

__global__ void gather_kernel(const float* __restrict__ x, const int* __restrict__ idx,
                              const int* __restrict__ rank, const int* __restrict__ off,
                              bf16_t* __restrict__ xg, int* __restrict__ tok_of_pos) {
  int n = blockIdx.x;
  int e = idx[n];
  int pos = off[e] + rank[n];
  if (threadIdx.x == 0) tok_of_pos[pos] = n;
  float4 v = ((const float4*)(x + (size_t)n * DDIM))[threadIdx.x];
  bf16x4 o;
  o[0] = (bf16_t)v.x; o[1] = (bf16_t)v.y; o[2] = (bf16_t)v.z; o[3] = (bf16_t)v.w;
  *(bf16x4*)(xg + (size_t)pos * DDIM + threadIdx.x * 4) = o;
}

// transpose+convert: src [E][R][C] f32 -> dst [E][C][R] bf16
__global__ __launch_bounds__(256) void wtrans_kernel(const float* __restrict__ src,
                                                     bf16_t* __restrict__ dst,
                                                     int R, int C) {
  __shared__ float t[128][65];
  int e = blockIdx.z;
  int c0 = blockIdx.x * 64, r0g = blockIdx.y * 128;
  int tid = threadIdx.x;
  const float* s = src + (size_t)e * R * C;
#pragma unroll
  for (int p = 0; p < 8; p++) {
    int r = (tid >> 4) + p * 16;
    int c4 = (tid & 15) * 4;
    float4 v = *(const float4*)&s[(size_t)(r0g + r) * C + c0 + c4];
    t[r][c4 + 0] = v.x;
    t[r][c4 + 1] = v.y;
    t[r][c4 + 2] = v.z;
    t[r][c4 + 3] = v.w;
  }
  __syncthreads();
  bf16_t* d = dst + (size_t)e * R * C;
  int w = tid >> 6, l = tid & 63;
#pragma unroll
  for (int itc = 0; itc < 2; itc++) {
#pragma unroll
    for (int it2 = 0; it2 < 2; it2++) {
      int c = (l >> 3) + 8 * w + 32 * itc;
      int r0 = (l & 7) * 8 + 64 * it2;
      bf16x8 o;
#pragma unroll
      for (int j = 0; j < 8; j++) o[j] = (bf16_t)t[r0 + j][c];
      *(bf16x8*)&d[(size_t)(c0 + c) * R + r0g + r0] = o;
    }
  }
}

// ---------------------------------------------------------------------------
// 256x256 grouped GEMM, BK=64 (2 k-halves of 32), 512 thr = 8 waves (2M x 4N),
// 8-phase schedule per 2 K-tiles with counted vmcnt (T3+T4) + setprio (T5).
// LDS: [dbuf 2][kh 2][mat A/B] blocks of 256x32 bf16 (16KB each) = 128 KB.
// Swizzle: within a 32-k row, 16B chunk_phys = chunk ^ (row&3); staged with
// linear LDS dest + inverse-swizzled global source (rule 21).
// Stage stream (tile T computed at phases 4T+1..4T+4):
//   phase 4T+1: (T+1) A kh1   phase 4T+2: (T+1) B kh1   [vmcnt(8)]
//   phase 4T+3: (T+2) A kh0   phase 4T+4: (T+2) B kh0   [vmcnt(8)]
// -> every half-tile has 4 phases in flight; overwrite of a region happens
//    >=1 barrier after its last read; vmcnt(8) two phases before first read.
// Hardening vs r0: stage k-offsets wrap mod KDIM (no OOB prefetch reads);
// vmcnt(0) drain after the loop (no LDS-DMA pending at s_endpgm).
// ---------------------------------------------------------------------------
#define BLK(d, kh, mat) ((((d)*2 + (kh)) * 2 + (mat)) * 8192)

#define STAGE(d, kh, mat, P, koff)                                          \
  {                                                                         \
    int kw = (koff) & (KDIM - 1);                                           \
    gld_lds16(&lds[BLK(d, kh, mat) + wave * 512], P[0] + kw);               \
    gld_lds16(&lds[BLK(d, kh, mat) + 4096 + wave * 512], P[1] + kw);        \
  }

#define READ_A(d, kh)                                                       \
  _Pragma("unroll") for (int mi = 0; mi < 8; mi++)                          \
      af[mi] = *(const bf16x8*)&lds[BLK(d, kh, 0) + aoff + mi * 512];

#define READ_B(d, kh, nh)                                                   \
  _Pragma("unroll") for (int nj = 0; nj < 2; nj++)                          \
      bfr[nj] = *(const bf16x8*)&lds[BLK(d, kh, 1) + boff + ((nh)*2 + nj) * 512];

#define MFMA16(nh)                                                          \
  _Pragma("unroll") for (int mi = 0; mi < 8; mi++)                          \
  _Pragma("unroll") for (int nj = 0; nj < 2; nj++)                          \
      acc[mi][(nh)*2 + nj] = __builtin_amdgcn_mfma_f32_16x16x32_bf16(       \
          af[mi], bfr[nj], acc[mi][(nh)*2 + nj], 0, 0, 0);

#define SYNC_MFMA(nh)                                                       \
  __builtin_amdgcn_s_barrier();                                             \
  asm volatile("s_waitcnt lgkmcnt(0)" ::: "memory");                        \
  __builtin_amdgcn_sched_barrier(0);                                        \
  __builtin_amdgcn_s_setprio(1);                                            \
  MFMA16(nh);                                                               \
  __builtin_amdgcn_s_setprio(0);

#define ENDP_ODD  asm volatile("s_barrier" ::: "memory");
#define ENDP_EVEN asm volatile("s_waitcnt vmcnt(8)\n\ts_barrier" ::: "memory");

template <int KDIM, int NCOLS, bool TO_BF16>
__global__ __launch_bounds__(512, 2) void gemm_kernel(
    const bf16_t* __restrict__ A, const bf16_t* __restrict__ Bt,
    const float* __restrict__ bias,
    const int* __restrict__ cnt, const int* __restrict__ off,
    const int* __restrict__ tok_of_pos,
    bf16_t* __restrict__ outb, float* __restrict__ outf) {
  constexpr int NT = NCOLS / 256;
  const int b = blockIdx.x;
  const int e = b & 7;          // expert pinned to one XCD (id%8 round-robin)
  const int t = b >> 3;
  const int nt = t % NT;
  const int mt = t / NT;

  const int count = cnt[e];
  if (mt * 256 >= count) return;
  const int base = off[e];

  __shared__ bf16_t lds[8 * 8192];  // 128 KB

  const int tid = threadIdx.x;
  const int lane = tid & 63;
  const int wave = tid >> 6;
  const int mrow = lane & 15;
  const int q = lane >> 4;
  const int wrow = (wave >> 2) * 128;
  const int wcol = (wave & 3) * 64;

  // staging: thread t covers (row t/4 + s*128, phys chunk t&3); logical
  // chunk = (t&3) ^ (row&3)  (row&3 identical for s=0,1)
  const int rs0 = tid >> 2;
  const int lch = (tid & 3) ^ (rs0 & 3);
  const bf16_t* pA[2];
  const bf16_t* pB[2];
#pragma unroll
  for (int s = 0; s < 2; s++) {
    int rs = rs0 + s * 128;
    int gr = base + mt * 256 + rs;
    if (gr > NTOK - 1) gr = NTOK - 1;  // clamp: garbage rows masked at store
    pA[s] = A + (size_t)gr * KDIM + lch * 8;
    pB[s] = Bt + ((size_t)e * NCOLS + nt * 256 + rs) * KDIM + lch * 8;
  }

  const int swz = (q ^ (mrow & 3)) * 8;
  const int aoff = (wrow + mrow) * 32 + swz;
  const int boff = (wcol + mrow) * 32 + swz;

  f32x4 acc[8][4] = {};
  bf16x8 af[8], bfr[2];

  float bs[4];
#pragma unroll
  for (int j = 0; j < 4; j++)
    bs[j] = bias[(size_t)e * NCOLS + nt * 256 + wcol + j * 16 + mrow];

  // prologue: tile0 (all 4 halves) + tile1 kh0 = 12 gld_lds
  STAGE(0, 0, 0, pA, 0);  STAGE(0, 0, 1, pB, 0);
  STAGE(0, 1, 0, pA, 32); STAGE(0, 1, 1, pB, 32);
  STAGE(1, 0, 0, pA, 64); STAGE(1, 0, 1, pB, 64);
  ENDP_EVEN;

  const int NIT = KDIM / 128;  // 2 K-tiles per iteration
#pragma unroll 1
  for (int it = 0; it < NIT; ++it) {
    const int k0 = it * 128;
    // phase 1: tile 2i kh0 nh0 ; stage (2i+1) A kh1 -> buf1
    READ_A(0, 0); READ_B(0, 0, 0);
    STAGE(1, 1, 0, pA, k0 + 96);
    SYNC_MFMA(0); ENDP_ODD;
    // phase 2: tile 2i kh0 nh1 ; stage (2i+1) B kh1
    READ_B(0, 0, 1);
    STAGE(1, 1, 1, pB, k0 + 96);
    SYNC_MFMA(1); ENDP_EVEN;
    // phase 3: tile 2i kh1 nh0 ; stage (2i+2) A kh0 -> buf0
    READ_A(0, 1); READ_B(0, 1, 0);
    STAGE(0, 0, 0, pA, k0 + 128);
    SYNC_MFMA(0); ENDP_ODD;
    // phase 4: tile 2i kh1 nh1 ; stage (2i+2) B kh0
    READ_B(0, 1, 1);
    STAGE(0, 0, 1, pB, k0 + 128);
    SYNC_MFMA(1); ENDP_EVEN;
    // phase 5: tile 2i+1 kh0 nh0 ; stage (2i+2) A kh1
    READ_A(1, 0); READ_B(1, 0, 0);
    STAGE(0, 1, 0, pA, k0 + 160);
    SYNC_MFMA(0); ENDP_ODD;
    // phase 6: tile 2i+1 kh0 nh1 ; stage (2i+2) B kh1
    READ_B(1, 0, 1);
    STAGE(0, 1, 1, pB, k0 + 160);
    SYNC_MFMA(1); ENDP_EVEN;
    // phase 7: tile 2i+1 kh1 nh0 ; stage (2i+3) A kh0 -> buf1
    READ_A(1, 1); READ_B(1, 1, 0);
    STAGE(1, 0, 0, pA, k0 + 192);
    SYNC_MFMA(0); ENDP_ODD;
    // phase 8: tile 2i+1 kh1 nh1 ; stage (2i+3) B kh0
    READ_B(1, 1, 1);
    STAGE(1, 0, 1, pB, k0 + 192);
    SYNC_MFMA(1); ENDP_EVEN;
  }
  // Drain all outstanding LDS-DMA before epilogue/endpgm: a wave must not
  // terminate with global_load_lds in flight (LDS could be re-assigned).
  asm volatile("s_waitcnt vmcnt(0)" ::: "memory");

  const int mlimit = count - mt * 256;
#pragma unroll
  for (int mi = 0; mi < 8; mi++) {
#pragma unroll
    for (int r = 0; r < 4; r++) {
      int ml = wrow + mi * 16 + q * 4 + r;
      if (ml < mlimit) {
        int prow = base + mt * 256 + ml;
        if constexpr (TO_BF16) {
          bf16_t* orow = outb + (size_t)prow * NCOLS + nt * 256;
#pragma unroll
          for (int j = 0; j < 4; j++)
            orow[wcol + j * 16 + mrow] = (bf16_t)(acc[mi][j][r] + bs[j]);
        } else {
          int tok = tok_of_pos[prow];
          float* orow = outf + (size_t)tok * OUTW + nt * 256;
#pragma unroll
          for (int j = 0; j < 4; j++)
            orow[wcol + j * 16 + mrow] = acc[mi][j][r] + bs[j];
        }
      }
    }
  }
}

extern "C" void kernel_launch(void* const* d_in, const int* in_sizes, int n_in,
                              void* d_out, int out_size, void* d_ws, size_t ws_size,
                              hipStream_t stream) {
  const float* x  = (const float*)d_in[0];
  const float* W1 = (const float*)d_in[1];
  const float* b1 = (const float*)d_in[2];
  const float* W2 = (const float*)d_in[3];
  const float* b2 = (const float*)d_in[4];
  const int* idx  = (const int*)d_in[5];
  float* out = (float*)d_out;

  char* ws = (char*)d_ws;
  bf16_t* xg  = (bf16_t*)(ws);                 // 16 MB  [N][D] bf16
  bf16_t* hg  = (bf16_t*)(ws + 16777216);      // 32 MB  [N][H] bf16
  bf16_t* Wt1 = (bf16_t*)(ws + 50331648);      // 32 MB  [E][H][D] bf16
  bf16_t* Wt2 = (bf16_t*)(ws + 83886080);      // 32 MB  [E][O][H] bf16
  int* tok    = (int*)(ws + 117440512);        // 32 KB
  int* rank   = (int*)(ws + 117473280);        // 32 KB
  int* cnt    = (int*)(ws + 117506048);
  int* off    = (int*)(ws + 117506080);

  zero_cnt_kernel<<<1, 64, 0, stream>>>(cnt);
  route_kernel<<<NTOK / 256, 256, 0, stream>>>(idx, out, rank, cnt);
  scan_kernel<<<1, 64, 0, stream>>>(cnt, off);
  gather_kernel<<<NTOK, 256, 0, stream>>>(x, idx, rank, off, xg, tok);
  wtrans_kernel<<<dim3(HDIM / 64, DDIM / 128, NEXP), 256, 0, stream>>>(W1, Wt1, DDIM, HDIM);
  wtrans_kernel<<<dim3(ODIM / 64, HDIM / 128, NEXP), 256, 0, stream>>>(W2, Wt2, HDIM, ODIM);
  // GEMM1: K=1024, N=2048 -> 8 nt x 32 mt x 8 e = 2048 blocks (~256 active)
  gemm_kernel<DDIM, HDIM, true>
      <<<NEXP * MT2 * (HDIM / 256), 512, 0, stream>>>(
      xg, Wt1, b1, cnt, off, tok, hg, nullptr);
  // GEMM2: K=2048, N=1024 -> 4 nt x 32 mt x 8 e = 1024 blocks (~128 active)
  gemm_kernel<HDIM, ODIM, false>
      <<<NEXP * MT2 * (ODIM / 256), 512, 0, stream>>>(
      hg, Wt2, b2, cnt, off, tok, nullptr, out);
}

// Round 3
// 326.628 us; speedup vs baseline: 1.0217x; 1.0217x over previous
//
#include <hip/hip_runtime.h>

#define NTOK 8192
#define DDIM 1024
#define HDIM 2048
#define ODIM 1024
#define NEXP 8
#define OUTW (ODIM + NEXP)   // 1032
#define MT_MAX 64            // worst-case m-tiles per expert (all tokens -> one expert)

typedef __bf16 bf16_t;
typedef bf16_t bf16x8 __attribute__((ext_vector_type(8)));
typedef bf16_t bf16x4 __attribute__((ext_vector_type(4)));
typedef float f32x4 __attribute__((ext_vector_type(4)));

__device__ __forceinline__ void gld_lds16(bf16_t* lds, const bf16_t* g) {
  __builtin_amdgcn_global_load_lds(
      (__attribute__((address_space(1))) void*)g,
      (__attribute__((address_space(3))) void*)lds, 16, 0, 0);
}

__global__ void zero_cnt_kernel(int* cnt) {
  if (threadIdx.x < NEXP) cnt[threadIdx.x] = 0;
}

// Per-block LDS histogram: 256 global atomics total instead of 8192.
__global__ void route_kernel(const int* __restrict__ idx, float* __restrict__ out,
                             int* __restrict__ rank, int* cnt) {
  __shared__ int lcnt[NEXP];
  __shared__ int lbase[NEXP];
  int t = threadIdx.x;
  if (t < NEXP) lcnt[t] = 0;
  __syncthreads();
  int n = blockIdx.x * 256 + t;
  int e = idx[n];
  int lr = atomicAdd(&lcnt[e], 1);
  __syncthreads();
  if (t < NEXP) lbase[t] = atomicAdd(&cnt[t], lcnt[t]);
  __syncthreads();
  rank[n] = lbase[e] + lr;
  float* o = out + (size_t)n * OUTW + ODIM;
#pragma unroll
  for (int j = 0; j < NEXP; j++) o[j] = (j == e) ? 1.0f : 0.0f;
}

__global__ void scan_kernel(const int* __restrict__ cnt, int* __restrict__ off) {
  if (threadIdx.x == 0) {
    int s = 0;
    for (int e = 0; e < NEXP; e++) { off[e] = s; s += cnt[e]; }
  }
}

__global__ void gather_kernel(const float* __restrict__ x, const int* __restrict__ idx,
                              const int* __restrict__ rank, const int* __restrict__ off,
                              bf16_t* __restrict__ xg, int* __restrict__ tok_of_pos) {
  int n = blockIdx.x;
  int e = idx[n];
  int pos = off[e] + rank[n];
  if (threadIdx.x == 0) tok_of_pos[pos] = n;
  float4 v = ((const float4*)(x + (size_t)n * DDIM))[threadIdx.x];
  bf16x4 o;
  o[0] = (bf16_t)v.x; o[1] = (bf16_t)v.y; o[2] = (bf16_t)v.z; o[3] = (bf16_t)v.w;
  *(bf16x4*)(xg + (size_t)pos * DDIM + threadIdx.x * 4) = o;
}

// transpose+convert both weight tensors in ONE launch:
//   blocks [0,2048):  W1 [E][1024][2048] f32 -> Wt1 [E][2048][1024] bf16
//   blocks [2048,4096): W2 [E][2048][1024] f32 -> Wt2 [E][1024][2048] bf16
// tile 128(r) x 64(c); 256B-segment reads, 16B/lane bf16x8 writes;
// LDS stride 65 words -> all LDS patterns 2-way (free).
__global__ __launch_bounds__(256) void wtrans2_kernel(
    const float* __restrict__ s1, bf16_t* __restrict__ d1,
    const float* __restrict__ s2, bf16_t* __restrict__ d2) {
  __shared__ float t[128][65];
  int b = blockIdx.x;
  const float* src; bf16_t* dst; int R, C, bx, by, e;
  if (b < 2048) {        // W1: C/64=32 x-tiles, R/128=8 y-tiles, 8 experts
    src = s1; dst = d1; R = DDIM; C = HDIM;
    bx = b & 31; by = (b >> 5) & 7; e = b >> 8;
  } else {               // W2: C/64=16 x-tiles, R/128=16 y-tiles, 8 experts
    int b2 = b - 2048;
    src = s2; dst = d2; R = HDIM; C = ODIM;
    bx = b2 & 15; by = (b2 >> 4) & 15; e = b2 >> 8;
  }
  int c0 = bx * 64, r0g = by * 128;
  int tid = threadIdx.x;
  const float* s = src + (size_t)e * R * C;
#pragma unroll
  for (int p = 0; p < 8; p++) {
    int r = (tid >> 4) + p * 16;
    int c4 = (tid & 15) * 4;
    float4 v = *(const float4*)&s[(size_t)(r0g + r) * C + c0 + c4];
    t[r][c4 + 0] = v.x;
    t[r][c4 + 1] = v.y;
    t[r][c4 + 2] = v.z;
    t[r][c4 + 3] = v.w;
  }
  __syncthreads();
  bf16_t* d = dst + (size_t)e * R * C;
  int w = tid >> 6, l = tid & 63;
#pragma unroll
  for (int itc = 0; itc < 2; itc++) {
#pragma unroll
    for (int it2 = 0; it2 < 2; it2++) {
      int c = (l >> 3) + 8 * w + 32 * itc;
      int r0 = (l & 7) * 8 + 64 * it2;
      bf16x8 o;
#pragma unroll
      for (int j = 0; j < 8; j++) o[j] = (bf16_t)t[r0 + j][c];
      *(bf16x8*)&d[(size_t)(c0 + c) * R + r0g + r0] = o;
    }
  }
}

// C[pos][n] = sum_k A[pos][k] * Bt[e][n][k] + bias[e][n]
// 1D grid, expert = blockIdx.x & 7  ->  expert pinned to one XCD (id%8 round-robin).
// XOR swizzle: staging lane loads global k-quarter (lane&3)^(row&3) so LDS slot
// (row, qs) holds global quarter qs^(row&3); fragment reads use slot q^(mrow&3).
// -> ds_read_b128 hits all 32 banks (8 lanes/bank-quad), conflict-free.
// 2-phase double-buffered K loop (T3-minimum, m248v2): issue next-tile
// global_load_lds FIRST, compute current tile, single __syncthreads per
// K-step (its vmcnt(0)+lgkmcnt(0) drain lands AFTER the MFMA block, so the
// stage latency hides under compute instead of being serially exposed).
template <int KDIM, int NCOLS, int MTG, bool TO_BF16>
__global__ __launch_bounds__(256) void gemm_kernel(
    const bf16_t* __restrict__ A, const bf16_t* __restrict__ Bt,
    const float* __restrict__ bias,
    const int* __restrict__ cnt, const int* __restrict__ off,
    const int* __restrict__ tok_of_pos,
    bf16_t* __restrict__ outb, float* __restrict__ outf) {
  constexpr int NT = NCOLS / 128;
  const int b = blockIdx.x;
  const int e = b & 7;
  int t = b >> 3;
  const int mtl = t % MTG;
  t /= MTG;
  const int nt = t % NT;
  const int g = t / NT;
  const int mt = g * MTG + mtl;

  const int count = cnt[e];
  if (mt * 128 >= count) return;
  const int base = off[e];

  __shared__ bf16_t lA[2][128 * 32];   // 2 x 8 KB
  __shared__ bf16_t lB[2][128 * 32];   // 2 x 8 KB   (32 KB total)

  const int tid = threadIdx.x;
  const int lane = tid & 63;
  const int wave = tid >> 6;
  const int mrow = lane & 15;
  const int q = lane >> 4;
  const int wm = (wave & 1) * 64;
  const int wn = (wave >> 1) * 64;

  // staging: chunk c = wave*2+s covers tile rows c*16..c*16+15;
  // lane -> (row c*16 + l>>2, k-quarter (l&3)^(row&3))   [XOR swizzle]
  const bf16_t* pA[2];
  const bf16_t* pB[2];
#pragma unroll
  for (int s = 0; s < 2; s++) {
    int lrow = wave * 32 + s * 16 + (lane >> 2);
    int kq = (lane & 3) ^ (lrow & 3);
    int gr = base + mt * 128 + lrow;
    if (gr > NTOK - 1) gr = NTOK - 1;  // clamp: garbage rows masked at store
    pA[s] = A + (size_t)gr * KDIM + kq * 8;
    int nrow = nt * 128 + lrow;
    pB[s] = Bt + ((size_t)e * NCOLS + nrow) * KDIM + kq * 8;
  }

  f32x4 acc[4][4] = {};
  const bf16_t* la0 = &lA[0][(wm + mrow) * 32 + ((q ^ (mrow & 3)) * 8)];
  const bf16_t* lb0 = &lB[0][(wn + mrow) * 32 + ((q ^ (mrow & 3)) * 8)];

  // prologue: stage k-tile 0 into buffer 0
#pragma unroll
  for (int s = 0; s < 2; s++) {
    gld_lds16(&lA[0][(wave * 2 + s) * 512], pA[s]);
    gld_lds16(&lB[0][(wave * 2 + s) * 512], pB[s]);
  }
  __syncthreads();  // drains vmcnt(0): buffer 0 ready

  int db = 0;
  for (int kk = 0; kk < KDIM; kk += 32) {
    if (kk + 32 < KDIM) {  // issue next-tile stage into the other buffer
#pragma unroll
      for (int s = 0; s < 2; s++) {
        gld_lds16(&lA[db ^ 1][(wave * 2 + s) * 512], pA[s] + kk + 32);
        gld_lds16(&lB[db ^ 1][(wave * 2 + s) * 512], pB[s] + kk + 32);
      }
    }
    bf16x8 af[4], bfr[4];
#pragma unroll
    for (int i = 0; i < 4; i++) {
      af[i]  = *(const bf16x8*)(la0 + db * 4096 + i * 16 * 32);
      bfr[i] = *(const bf16x8*)(lb0 + db * 4096 + i * 16 * 32);
    }
#pragma unroll
    for (int i = 0; i < 4; i++)
#pragma unroll
      for (int j = 0; j < 4; j++)
        acc[i][j] = __builtin_amdgcn_mfma_f32_16x16x32_bf16(af[i], bfr[j], acc[i][j], 0, 0, 0);
    // single barrier per K-step: its implicit vmcnt(0)+lgkmcnt(0) drain
    // (a) completes the next-tile stage issued above (latency hidden under
    // the MFMAs), (b) retires all reads of buf db before it is re-staged
    // next iteration. No pending LDS-DMA at endpgm (last iter stages nothing).
    __syncthreads();
    db ^= 1;
  }

  const int mlimit = count - mt * 128;
  float bs[4];
#pragma unroll
  for (int j = 0; j < 4; j++)
    bs[j] = bias[(size_t)e * NCOLS + nt * 128 + wn + j * 16 + mrow];

#pragma unroll
  for (int i = 0; i < 4; i++) {
#pragma unroll
    for (int r = 0; r < 4; r++) {
      int ml = wm + i * 16 + q * 4 + r;
      if (ml < mlimit) {
        int prow = base + mt * 128 + ml;
        if constexpr (TO_BF16) {
          bf16_t* orow = outb + (size_t)prow * NCOLS;
#pragma unroll
          for (int j = 0; j < 4; j++)
            orow[nt * 128 + wn + j * 16 + mrow] = (bf16_t)(acc[i][j][r] + bs[j]);
        } else {
          int tok = tok_of_pos[prow];
          float* orow = outf + (size_t)tok * OUTW;
#pragma unroll
          for (int j = 0; j < 4; j++)
            orow[nt * 128 + wn + j * 16 + mrow] = acc[i][j][r] + bs[j];
        }
      }
    }
  }
}

extern "C" void kernel_launch(void* const* d_in, const int* in_sizes, int n_in,
                              void* d_out, int out_size, void* d_ws, size_t ws_size,
                              hipStream_t stream) {
  const float* x  = (const float*)d_in[0];
  const float* W1 = (const float*)d_in[1];
  const float* b1 = (const float*)d_in[2];
  const float* W2 = (const float*)d_in[3];
  const float* b2 = (const float*)d_in[4];
  const int* idx  = (const int*)d_in[5];
  float* out = (float*)d_out;

  char* ws = (char*)d_ws;
  bf16_t* xg  = (bf16_t*)(ws);                 // 16 MB  [N][D] bf16
  bf16_t* hg  = (bf16_t*)(ws + 16777216);      // 32 MB  [N][H] bf16
  bf16_t* Wt1 = (bf16_t*)(ws + 50331648);      // 32 MB  [E][H][D] bf16
  bf16_t* Wt2 = (bf16_t*)(ws + 83886080);      // 32 MB  [E][O][H] bf16
  int* tok    = (int*)(ws + 117440512);        // 32 KB
  int* rank   = (int*)(ws + 117473280);        // 32 KB
  int* cnt    = (int*)(ws + 117506048);
  int* off    = (int*)(ws + 117506080);

  zero_cnt_kernel<<<1, 64, 0, stream>>>(cnt);
  route_kernel<<<NTOK / 256, 256, 0, stream>>>(idx, out, rank, cnt);
  scan_kernel<<<1, 64, 0, stream>>>(cnt, off);
  gather_kernel<<<NTOK, 256, 0, stream>>>(x, idx, rank, off, xg, tok);
  // both weight transposes in one launch (4096 blocks)
  wtrans2_kernel<<<4096, 256, 0, stream>>>(W1, Wt1, W2, Wt2);
  // GEMM1: K=1024, NCOLS=2048, MTG=8 (8*128 rows * 1024 k * 2B = 2MB A-group)
  gemm_kernel<DDIM, HDIM, 8, true>
      <<<NEXP * MT_MAX * (HDIM / 128), 256, 0, stream>>>(
      xg, Wt1, b1, cnt, off, tok, hg, nullptr);
  // GEMM2: K=2048, NCOLS=1024, MTG=4 (4*128 rows * 2048 k * 2B = 2MB A-group)
  gemm_kernel<HDIM, ODIM, 4, false>
      <<<NEXP * MT_MAX * (ODIM / 128), 256, 0, stream>>>(
      hg, Wt2, b2, cnt, off, tok, nullptr, out);
}

// Round 4
// 311.222 us; speedup vs baseline: 1.0723x; 1.0495x over previous
//
#include <hip/hip_runtime.h>

#define NTOK 8192
#define DDIM 1024
#define HDIM 2048
#define ODIM 1024
#define NEXP 8
#define OUTW (ODIM + NEXP)   // 1032
#define MT_MAX 64            // worst-case m-tiles per expert (all tokens -> one expert)

typedef __bf16 bf16_t;
typedef bf16_t bf16x8 __attribute__((ext_vector_type(8)));
typedef bf16_t bf16x4 __attribute__((ext_vector_type(4)));
typedef float f32x4 __attribute__((ext_vector_type(4)));

__device__ __forceinline__ void gld_lds16(bf16_t* lds, const bf16_t* g) {
  __builtin_amdgcn_global_load_lds(
      (__attribute__((address_space(1))) void*)g,
      (__attribute__((address_space(3))) void*)lds, 16, 0, 0);
}

// Per-block LDS histogram: 256 global atomics total instead of 8192.
__global__ void route_kernel(const int* __restrict__ idx, float* __restrict__ out,
                             int* __restrict__ rank, int* cnt) {
  __shared__ int lcnt[NEXP];
  __shared__ int lbase[NEXP];
  int t = threadIdx.x;
  if (t < NEXP) lcnt[t] = 0;
  __syncthreads();
  int n = blockIdx.x * 256 + t;
  int e = idx[n];
  int lr = atomicAdd(&lcnt[e], 1);
  __syncthreads();
  if (t < NEXP) lbase[t] = atomicAdd(&cnt[t], lcnt[t]);
  __syncthreads();
  rank[n] = lbase[e] + lr;
  float* o = out + (size_t)n * OUTW + ODIM;
#pragma unroll
  for (int j = 0; j < NEXP; j++) o[j] = (j == e) ? 1.0f : 0.0f;
}

// off[e] is an 8-element prefix sum; recomputed per block from cnt (L2-hot)
// instead of a dedicated 1-block scan launch.
__device__ __forceinline__ void prefix_of(const int* cnt, int e, int& base, int& count) {
  base = 0; count = 0;
#pragma unroll
  for (int j = 0; j < NEXP; j++) {
    int c = cnt[j];
    if (j < e) base += c;
    if (j == e) count = c;
  }
}

__global__ void gather_kernel(const float* __restrict__ x, const int* __restrict__ idx,
                              const int* __restrict__ rank, const int* __restrict__ cnt,
                              bf16_t* __restrict__ xg, int* __restrict__ tok_of_pos) {
  int n = blockIdx.x;
  int e = idx[n];
  int base, count;
  prefix_of(cnt, e, base, count);
  int pos = base + rank[n];
  if (threadIdx.x == 0) tok_of_pos[pos] = n;
  float4 v = ((const float4*)(x + (size_t)n * DDIM))[threadIdx.x];
  bf16x4 o;
  o[0] = (bf16_t)v.x; o[1] = (bf16_t)v.y; o[2] = (bf16_t)v.z; o[3] = (bf16_t)v.w;
  *(bf16x4*)(xg + (size_t)pos * DDIM + threadIdx.x * 4) = o;
}

// transpose+convert both weight tensors in ONE launch:
//   blocks [0,2048):  W1 [E][1024][2048] f32 -> Wt1 [E][2048][1024] bf16
//   blocks [2048,4096): W2 [E][2048][1024] f32 -> Wt2 [E][1024][2048] bf16
// tile 128(r) x 64(c); 256B-segment reads, 16B/lane bf16x8 writes;
// LDS stride 65 words -> all LDS patterns 2-way (free).
__global__ __launch_bounds__(256) void wtrans2_kernel(
    const float* __restrict__ s1, bf16_t* __restrict__ d1,
    const float* __restrict__ s2, bf16_t* __restrict__ d2) {
  __shared__ float t[128][65];
  int b = blockIdx.x;
  const float* src; bf16_t* dst; int R, C, bx, by, e;
  if (b < 2048) {        // W1: C/64=32 x-tiles, R/128=8 y-tiles, 8 experts
    src = s1; dst = d1; R = DDIM; C = HDIM;
    bx = b & 31; by = (b >> 5) & 7; e = b >> 8;
  } else {               // W2: C/64=16 x-tiles, R/128=16 y-tiles, 8 experts
    int b2 = b - 2048;
    src = s2; dst = d2; R = HDIM; C = ODIM;
    bx = b2 & 15; by = (b2 >> 4) & 15; e = b2 >> 8;
  }
  int c0 = bx * 64, r0g = by * 128;
  int tid = threadIdx.x;
  const float* s = src + (size_t)e * R * C;
#pragma unroll
  for (int p = 0; p < 8; p++) {
    int r = (tid >> 4) + p * 16;
    int c4 = (tid & 15) * 4;
    float4 v = *(const float4*)&s[(size_t)(r0g + r) * C + c0 + c4];
    t[r][c4 + 0] = v.x;
    t[r][c4 + 1] = v.y;
    t[r][c4 + 2] = v.z;
    t[r][c4 + 3] = v.w;
  }
  __syncthreads();
  bf16_t* d = dst + (size_t)e * R * C;
  int w = tid >> 6, l = tid & 63;
#pragma unroll
  for (int itc = 0; itc < 2; itc++) {
#pragma unroll
    for (int it2 = 0; it2 < 2; it2++) {
      int c = (l >> 3) + 8 * w + 32 * itc;
      int r0 = (l & 7) * 8 + 64 * it2;
      bf16x8 o;
#pragma unroll
      for (int j = 0; j < 8; j++) o[j] = (bf16_t)t[r0 + j][c];
      *(bf16x8*)&d[(size_t)(c0 + c) * R + r0g + r0] = o;
    }
  }
}

// C[pos][n] = sum_k A[pos][k] * Bt[e][n][k] + bias[e][n]
// 1D grid, expert = blockIdx.x & 7  ->  expert pinned to one XCD (id%8 round-robin).
// XOR swizzle: staging lane loads global k-quarter (lane&3)^(row&3) so LDS slot
// (row, qs) holds global quarter qs^(row&3); fragment reads use slot q^(mrow&3).
// -> ds_read_b128 hits all 32 banks (8 lanes/bank-quad), conflict-free.
// Proven round-0 schedule: single 16KB-per-matrix buffer, stage -> barrier ->
// compute -> barrier. (Both 2-phase and 8-phase prefetch variants measured
// ~12% SLOWER: cross-block TLP at 4 blocks/CU already hides stage latency.)
template <int KDIM, int NCOLS, int MTG, bool TO_BF16>
__global__ __launch_bounds__(256) void gemm_kernel(
    const bf16_t* __restrict__ A, const bf16_t* __restrict__ Bt,
    const float* __restrict__ bias,
    const int* __restrict__ cnt,
    const int* __restrict__ tok_of_pos,
    bf16_t* __restrict__ outb, float* __restrict__ outf) {
  constexpr int NT = NCOLS / 128;
  const int b = blockIdx.x;
  const int e = b & 7;
  int t = b >> 3;
  const int mtl = t % MTG;
  t /= MTG;
  const int nt = t % NT;
  const int g = t / NT;
  const int mt = g * MTG + mtl;

  int base, count;
  prefix_of(cnt, e, base, count);
  if (mt * 128 >= count) return;

  __shared__ bf16_t lA[128 * 32];
  __shared__ bf16_t lB[128 * 32];

  const int tid = threadIdx.x;
  const int lane = tid & 63;
  const int wave = tid >> 6;
  const int mrow = lane & 15;
  const int q = lane >> 4;
  const int wm = (wave & 1) * 64;
  const int wn = (wave >> 1) * 64;

  // staging: chunk c = wave*2+s covers tile rows c*16..c*16+15;
  // lane -> (row c*16 + l>>2, k-quarter (l&3)^(row&3))   [XOR swizzle]
  const bf16_t* pA[2];
  const bf16_t* pB[2];
#pragma unroll
  for (int s = 0; s < 2; s++) {
    int lrow = wave * 32 + s * 16 + (lane >> 2);
    int kq = (lane & 3) ^ (lrow & 3);
    int gr = base + mt * 128 + lrow;
    if (gr > NTOK - 1) gr = NTOK - 1;  // clamp: garbage rows masked at store
    pA[s] = A + (size_t)gr * KDIM + kq * 8;
    int nrow = nt * 128 + lrow;
    pB[s] = Bt + ((size_t)e * NCOLS + nrow) * KDIM + kq * 8;
  }

  f32x4 acc[4][4] = {};
  const bf16_t* la0 = &lA[(wm + mrow) * 32 + ((q ^ (mrow & 3)) * 8)];
  const bf16_t* lb0 = &lB[(wn + mrow) * 32 + ((q ^ (mrow & 3)) * 8)];

  for (int kk = 0; kk < KDIM; kk += 32) {
#pragma unroll
    for (int s = 0; s < 2; s++) {
      gld_lds16(&lA[(wave * 2 + s) * 512], pA[s] + kk);
      gld_lds16(&lB[(wave * 2 + s) * 512], pB[s] + kk);
    }
    __syncthreads();
    bf16x8 af[4], bfr[4];
#pragma unroll
    for (int i = 0; i < 4; i++) {
      af[i]  = *(const bf16x8*)(la0 + i * 16 * 32);
      bfr[i] = *(const bf16x8*)(lb0 + i * 16 * 32);
    }
#pragma unroll
    for (int i = 0; i < 4; i++)
#pragma unroll
      for (int j = 0; j < 4; j++)
        acc[i][j] = __builtin_amdgcn_mfma_f32_16x16x32_bf16(af[i], bfr[j], acc[i][j], 0, 0, 0);
    __syncthreads();
  }

  const int mlimit = count - mt * 128;
  float bs[4];
#pragma unroll
  for (int j = 0; j < 4; j++)
    bs[j] = bias[(size_t)e * NCOLS + nt * 128 + wn + j * 16 + mrow];

#pragma unroll
  for (int i = 0; i < 4; i++) {
#pragma unroll
    for (int r = 0; r < 4; r++) {
      int ml = wm + i * 16 + q * 4 + r;
      if (ml < mlimit) {
        int prow = base + mt * 128 + ml;
        if constexpr (TO_BF16) {
          bf16_t* orow = outb + (size_t)prow * NCOLS;
#pragma unroll
          for (int j = 0; j < 4; j++)
            orow[nt * 128 + wn + j * 16 + mrow] = (bf16_t)(acc[i][j][r] + bs[j]);
        } else {
          int tok = tok_of_pos[prow];
          float* orow = outf + (size_t)tok * OUTW;
#pragma unroll
          for (int j = 0; j < 4; j++)
            orow[nt * 128 + wn + j * 16 + mrow] = acc[i][j][r] + bs[j];
        }
      }
    }
  }
}

extern "C" void kernel_launch(void* const* d_in, const int* in_sizes, int n_in,
                              void* d_out, int out_size, void* d_ws, size_t ws_size,
                              hipStream_t stream) {
  const float* x  = (const float*)d_in[0];
  const float* W1 = (const float*)d_in[1];
  const float* b1 = (const float*)d_in[2];
  const float* W2 = (const float*)d_in[3];
  const float* b2 = (const float*)d_in[4];
  const int* idx  = (const int*)d_in[5];
  float* out = (float*)d_out;

  char* ws = (char*)d_ws;
  bf16_t* xg  = (bf16_t*)(ws);                 // 16 MB  [N][D] bf16
  bf16_t* hg  = (bf16_t*)(ws + 16777216);      // 32 MB  [N][H] bf16
  bf16_t* Wt1 = (bf16_t*)(ws + 50331648);      // 32 MB  [E][H][D] bf16
  bf16_t* Wt2 = (bf16_t*)(ws + 83886080);      // 32 MB  [E][O][H] bf16
  int* tok    = (int*)(ws + 117440512);        // 32 KB
  int* rank   = (int*)(ws + 117473280);        // 32 KB
  int* cnt    = (int*)(ws + 117506048);

  // 6 dispatches total (was 8): memset replaces zero_cnt; scan folded into
  // consumers (8-element prefix recomputed per block from L2-hot cnt).
  hipMemsetAsync(cnt, 0, NEXP * sizeof(int), stream);
  route_kernel<<<NTOK / 256, 256, 0, stream>>>(idx, out, rank, cnt);
  gather_kernel<<<NTOK, 256, 0, stream>>>(x, idx, rank, cnt, xg, tok);
  // both weight transposes in one launch (4096 blocks)
  wtrans2_kernel<<<4096, 256, 0, stream>>>(W1, Wt1, W2, Wt2);
  // GEMM1: K=1024, NCOLS=2048, MTG=8 (8*128 rows * 1024 k * 2B = 2MB A-group)
  gemm_kernel<DDIM, HDIM, 8, true>
      <<<NEXP * MT_MAX * (HDIM / 128), 256, 0, stream>>>(
      xg, Wt1, b1, cnt, tok, hg, nullptr);
  // GEMM2: K=2048, NCOLS=1024, MTG=4 (4*128 rows * 2048 k * 2B = 2MB A-group)
  gemm_kernel<HDIM, ODIM, 4, false>
      <<<NEXP * MT_MAX * (ODIM / 128), 256, 0, stream>>>(
      hg, Wt2, b2, cnt, tok, nullptr, out);
}